// Round 6
// baseline (1738.587 us; speedup 1.0000x reference)
//
#include <hip/hip_runtime.h>
#include <hip/hip_bf16.h>

#define NSITES 256
#define NM 128        // nup == ndn
#define NMODES 512
#define NS 64         // super-iterations (2 columns each)

typedef unsigned long long u64;
typedef unsigned int u32;

#define REP8(M)    M(0) M(1) M(2) M(3) M(4) M(5) M(6) M(7)
#define REP8P(M,P) M(0,P) M(1,P) M(2,P) M(3,P) M(4,P) M(5,P) M(6,P) M(7,P)

// DPP max-reduce step: all-VALU cross-lane.
template<int CTRL>
__device__ __forceinline__ float dpp_max(float x) {
  const int xi = __float_as_int(x);
  const int yi = __builtin_amdgcn_update_dpp(xi, xi, CTRL, 0xF, 0xF, false);
  return fmaxf(x, __int_as_float(yi));
}
// Wave-wide max of x, broadcast to all lanes.
__device__ __forceinline__ float wave_max(float x) {
  x = dpp_max<0x128>(x);   // row_ror:8
  x = dpp_max<0x124>(x);   // row_ror:4
  x = dpp_max<0x122>(x);   // row_ror:2
  x = dpp_max<0x121>(x);   // row_ror:1
  x = dpp_max<0x142>(x);   // row_bcast15
  x = dpp_max<0x143>(x);   // row_bcast31 -> lane 63 has global max
  return __int_as_float(__builtin_amdgcn_readlane(__float_as_int(x), 63));
}
// Read element p (0..127) of a column stored as (x1: rows 0..63, x2: rows 64..127).
// p is wave-uniform.
__device__ __forceinline__ float rl2(float x1, float x2, int p) {
  const int v1 = __builtin_amdgcn_readlane(__float_as_int(x1), p & 63);
  const int v2 = __builtin_amdgcn_readlane(__float_as_int(x2), p & 63);
  return __int_as_float(p < 64 ? v1 : v2);
}

// One block per (batch, spin). 256 threads, register-resident 128x128 LU,
// partial pivoting, pivot-retirement (no physical swaps), RANK-2 super-steps:
// both pivots of a column pair are resolved fully in registers (every wave
// holds complete copies of pivot columns c,d), so only ONE barrier per TWO
// columns. Trailing update: a -= cI*raw1 + m'I*raw2, cI = mI - mp*m'I.
// Already-finalized columns may receive garbage updates - harmless, they are
// never read again (only pivots feed the output).
// ALL register indices are preprocessor literals (SROA runs before unrolling).
__global__ __launch_bounds__(256, 2) void lu_kernel(
    const int* __restrict__ n, const float* __restrict__ phi_up,
    const float* __restrict__ phi_dn, float* __restrict__ ws, int B)
{
  __shared__ int occ[NSITES];
  __shared__ int wcnt[4];
  __shared__ float colbuf[2][2][NM];   // [parity][which][row]
  __shared__ float rowP[2][2][NM];     // [parity][which][col]
  __shared__ int ipiv[NM];

  const int t = threadIdx.x;
  const int tx = t & 15, ty = t >> 4;
  const int lane = t & 63, wv = t >> 6;
  const int bs = blockIdx.x;
  const int b = bs >> 1, spin = bs & 1;
  const int* nn = n + b * NMODES + spin * NSITES;
  const float* phi = spin ? phi_dn : phi_up;

  // ---- occupied-site list (exactly NM entries, ascending) ----
  {
    int v = nn[t];
    u64 m = __ballot(v != 0);
    if (lane == 0) wcnt[wv] = __popcll(m);
    __syncthreads();
    int off = 0;
    for (int w = 0; w < wv; ++w) off += wcnt[w];
    if (v) occ[off + __popcll(m & ((1ull << lane) - 1))] = t;
    __syncthreads();
  }

  // ---- gather matrix into registers (static indices only) ----
  float a[8][8];
#define GATH(II) { const float* pr_ = phi + occ[(II)*16 + ty] * NM; \
  a[II][0] = pr_[0*16+tx]; a[II][1] = pr_[1*16+tx]; \
  a[II][2] = pr_[2*16+tx]; a[II][3] = pr_[3*16+tx]; \
  a[II][4] = pr_[4*16+tx]; a[II][5] = pr_[5*16+tx]; \
  a[II][6] = pr_[6*16+tx]; a[II][7] = pr_[7*16+tx]; }
  REP8(GATH)
#undef GATH

  // ---- prologue: cols 0,1 -> colbuf[1], cols 2,3 -> colbuf[0] ----
#define PUBP(II, DST) DST[(II)*16 + ty] = a[II][0];
  if (tx == 0) { float* d_ = &colbuf[1][0][0]; REP8P(PUBP, d_) }
  if (tx == 1) { float* d_ = &colbuf[1][1][0]; REP8P(PUBP, d_) }
  if (tx == 2) { float* d_ = &colbuf[0][0][0]; REP8P(PUBP, d_) }
  if (tx == 3) { float* d_ = &colbuf[0][1][0]; REP8P(PUBP, d_) }
#undef PUBP
  __syncthreads();

  float c1 = colbuf[1][0][lane], c2 = colbuf[1][0][lane + 64];
  float d1 = colbuf[1][1][lane], d2 = colbuf[1][1][lane + 64];
  int r1 = 0, r2 = 0;           // retirement flags for rows lane, lane+64
  float l2sum = 0.f;
  int sb = 0;
  const int bidx0 = (ty) << 2;          // bpermute byte-indices
  const int bidx1 = (16 + ty) << 2;
  const int bidx2 = (32 + ty) << 2;
  const int bidx3 = (48 + ty) << 2;

  for (int s = 0; s < NS; ++s) {
    const int pp = s & 1;
    const int k0 = 2 * s;

    // ================= P1 (all-register): two pivots ======================
    // pivot 1 (column k0)
    const float ca1 = r1 ? -1.0f : fabsf(c1);
    const float ca2 = r2 ? -1.0f : fabsf(c2);
    const float mx1 = wave_max(fmaxf(ca1, ca2));
    const u64 A1 = __ballot(ca1 == mx1);
    const u64 A2 = __ballot(ca2 == mx1);
    int p1 = A1 ? (__ffsll(A1) - 1) : (__ffsll(A2) + 63);
    p1 = __builtin_amdgcn_readfirstlane(p1);
    const float piv1 = rl2(c1, c2, p1);
    const float rp1 = __builtin_amdgcn_rcpf(piv1);
    r1 |= (p1 == lane);
    r2 |= (p1 == lane + 64);
    const float m1a = r1 ? 0.f : c1 * rp1;
    const float m1b = r2 ? 0.f : c2 * rp1;

    // bring column k0+1 through step k0 (in regs)
    const float ud = rl2(d1, d2, p1);
    d1 = fmaf(-m1a, ud, d1);
    d2 = fmaf(-m1b, ud, d2);

    // pivot 2 (column k0+1)
    const float da1 = r1 ? -1.0f : fabsf(d1);
    const float da2 = r2 ? -1.0f : fabsf(d2);
    const float mx2 = wave_max(fmaxf(da1, da2));
    const u64 B1 = __ballot(da1 == mx2);
    const u64 B2 = __ballot(da2 == mx2);
    int p2 = B1 ? (__ffsll(B1) - 1) : (__ffsll(B2) + 63);
    p2 = __builtin_amdgcn_readfirstlane(p2);
    const float piv2 = rl2(d1, d2, p2);
    const float rp2 = __builtin_amdgcn_rcpf(piv2);
    r1 |= (p2 == lane);
    r2 |= (p2 == lane + 64);
    const float m2a = r1 ? 0.f : d1 * rp2;
    const float m2b = r2 ? 0.f : d2 * rp2;
    const float mp = rl2(m1a, m1b, p2);   // m[p2]: cross-term scalar

    // stage RAW pivot rows (updated through k0-1) for the rank-2 update
    const int pb1 = p1 >> 4, pt1 = p1 & 15;
    const int pb2 = p2 >> 4, pt2 = p2 & 15;
#define SRX(II, DST) case II: \
  DST[0*16+tx]=a[II][0]; DST[1*16+tx]=a[II][1]; DST[2*16+tx]=a[II][2]; DST[3*16+tx]=a[II][3]; \
  DST[4*16+tx]=a[II][4]; DST[5*16+tx]=a[II][5]; DST[6*16+tx]=a[II][6]; DST[7*16+tx]=a[II][7]; break;
    if (s < NS - 1) {
      if (ty == pt1) {
        float* d_ = &rowP[pp][0][0];
        switch (pb1) { REP8P(SRX, d_) }
      }
      if (ty == pt2) {
        float* d_ = &rowP[pp][1][0];
        switch (pb2) { REP8P(SRX, d_) }
      }
    }
#undef SRX
    if (t == 0) { ipiv[k0] = p1; ipiv[k0 + 1] = p2; }
    l2sum += __log2f(mx1) + __log2f(mx2);
    sb ^= (int)((__float_as_uint(piv1) ^ __float_as_uint(piv2)) >> 31);

    __syncthreads();   // the ONLY barrier per 2 columns
    if (s == NS - 1) break;

    // ================= P2: rank-2 trailing update =========================
    float mA[8], mB[8];
#define BPA(II) mA[II] = __int_as_float(__builtin_amdgcn_ds_bpermute( \
    ((II)&3)==0 ? bidx0 : ((II)&3)==1 ? bidx1 : ((II)&3)==2 ? bidx2 : bidx3, \
    __float_as_int((II) < 4 ? m1a : m1b)));
#define BPB(II) mB[II] = __int_as_float(__builtin_amdgcn_ds_bpermute( \
    ((II)&3)==0 ? bidx0 : ((II)&3)==1 ? bidx1 : ((II)&3)==2 ? bidx2 : bidx3, \
    __float_as_int((II) < 4 ? m2a : m2b)));
    REP8(BPA)
    REP8(BPB)
#undef BPA
#undef BPB
    // compose: cI = mI - mp*m'I  (stored back into mA)
#define CMP(II) mA[II] = fmaf(-mp, mB[II], mA[II]);
    REP8(CMP)
#undef CMP

    const int T = (k0 + 2) >> 4;
    float pr1[8], pr2[8];
#define PRE2(JJ, KB) if ((JJ) >= (KB)) { \
  pr1[JJ] = rowP[pp][0][(JJ)*16 + tx]; pr2[JJ] = rowP[pp][1][(JJ)*16 + tx]; }
#define UPD2(II, KB) { \
  if (0 >= (KB)) a[II][0] = fmaf(-mB[II], pr2[0], fmaf(-mA[II], pr1[0], a[II][0])); \
  if (1 >= (KB)) a[II][1] = fmaf(-mB[II], pr2[1], fmaf(-mA[II], pr1[1], a[II][1])); \
  if (2 >= (KB)) a[II][2] = fmaf(-mB[II], pr2[2], fmaf(-mA[II], pr1[2], a[II][2])); \
  if (3 >= (KB)) a[II][3] = fmaf(-mB[II], pr2[3], fmaf(-mA[II], pr1[3], a[II][3])); \
  if (4 >= (KB)) a[II][4] = fmaf(-mB[II], pr2[4], fmaf(-mA[II], pr1[4], a[II][4])); \
  if (5 >= (KB)) a[II][5] = fmaf(-mB[II], pr2[5], fmaf(-mA[II], pr1[5], a[II][5])); \
  if (6 >= (KB)) a[II][6] = fmaf(-mB[II], pr2[6], fmaf(-mA[II], pr1[6], a[II][6])); \
  if (7 >= (KB)) a[II][7] = fmaf(-mB[II], pr2[7], fmaf(-mA[II], pr1[7], a[II][7])); }
#define LUC2(KB) case KB: { REP8P(PRE2, KB) REP8P(UPD2, KB) } break;
    switch (T) {
      REP8(LUC2)
    }
#undef LUC2
#undef UPD2
#undef PRE2

    // ---- new pivot columns k0+2, k0+3: colbuf -> regs, 2 in-reg steps ----
    {
      float e1 = colbuf[pp][0][lane], e2 = colbuf[pp][0][lane + 64];
      float u = rl2(e1, e2, p1);
      e1 = fmaf(-m1a, u, e1); e2 = fmaf(-m1b, u, e2);
      u = rl2(e1, e2, p2);
      c1 = fmaf(-m2a, u, e1); c2 = fmaf(-m2b, u, e2);
      float f1 = colbuf[pp][1][lane], f2 = colbuf[pp][1][lane + 64];
      u = rl2(f1, f2, p1);
      f1 = fmaf(-m1a, u, f1); f2 = fmaf(-m1b, u, f2);
      u = rl2(f1, f2, p2);
      d1 = fmaf(-m2a, u, f1); d2 = fmaf(-m2b, u, f2);
    }

    // ---- publish cols k0+4, k0+5 into colbuf[pp^1] ----
    if (s <= NS - 3) {
      const int j4 = k0 + 4;
      const int c4l = j4 & 15;       // j4 even => c4l <= 14, same reg column
      const int sel = (tx == c4l) ? 0 : ((tx == c4l + 1) ? 1 : -1);
      if (sel >= 0) {
        float* dst = &colbuf[pp ^ 1][sel][0];
        switch (j4 >> 4) {
#define PUBJ(JJ) case JJ: \
  dst[0*16+ty]=a[0][JJ]; dst[1*16+ty]=a[1][JJ]; dst[2*16+ty]=a[2][JJ]; dst[3*16+ty]=a[3][JJ]; \
  dst[4*16+ty]=a[4][JJ]; dst[5*16+ty]=a[5][JJ]; dst[6*16+ty]=a[6][JJ]; dst[7*16+ty]=a[7][JJ]; break;
          REP8(PUBJ)
#undef PUBJ
        }
      }
    }
  }

  // ---- permutation parity from pivot sequence (inversion count) ----
  __syncthreads();
  int inv = 0;
  if (t < NM) {
    const int my = ipiv[t];
    for (int l = t + 1; l < NM; ++l) inv += (my > ipiv[l]) ? 1 : 0;
  }
  const u64 bal = __ballot((t < NM) && (inv & 1));
  if (lane == 0) wcnt[wv] = __popcll(bal);
  __syncthreads();

  if (t == 0) {
    const int par = (wcnt[0] + wcnt[1] + wcnt[2] + wcnt[3]) & 1;
    const int s = (sb ^ par) & 1;
    ws[B + spin * B + b] = l2sum * 0.6931471805599453f;   // logabs: [B, 3B)
    ws[3 * B + spin * B + b] = s ? -1.f : 1.f;            // sign:   [3B, 5B)
  }
}

// One block per batch: log_j = -0.5 * sum_{i occ} sum_c v[i][c] * nf[c]
__global__ __launch_bounds__(256) void jastrow_kernel(
    const int* __restrict__ n, const float* __restrict__ v,
    float* __restrict__ ws, int B)
{
  __shared__ int occ[256];
  __shared__ float nf[NMODES];
  __shared__ int wcnt[8];
  __shared__ float red[256];
  const int t = threadIdx.x, b = blockIdx.x;
  const int lane = t & 63, wv = t >> 6;
  const int* nn = n + b * NMODES;
  int v0 = nn[t], v1 = nn[256 + t];
  nf[t] = (float)v0;
  nf[256 + t] = (float)v1;
  u64 m0 = __ballot(v0 != 0), m1 = __ballot(v1 != 0);
  if (lane == 0) { wcnt[wv] = __popcll(m0); wcnt[4 + wv] = __popcll(m1); }
  __syncthreads();
  int off0 = 0;
  for (int w = 0; w < wv; ++w) off0 += wcnt[w];
  int base1 = wcnt[0] + wcnt[1] + wcnt[2] + wcnt[3];
  int off1 = base1;
  for (int w = 0; w < wv; ++w) off1 += wcnt[4 + w];
  if (v0) occ[off0 + __popcll(m0 & ((1ull << lane) - 1))] = t;
  if (v1) occ[off1 + __popcll(m1 & ((1ull << lane) - 1))] = 256 + t;
  __syncthreads();

  float acc = 0.f;
  for (int r = wv * 64; r < wv * 64 + 64; ++r) {
    const float* row = v + occ[r] * NMODES;   // occ[r] wave-uniform -> broadcast
#pragma unroll
    for (int cc = 0; cc < 8; ++cc) {
      int c = cc * 64 + lane;                 // coalesced 256B per iter
      acc += row[c] * nf[c];
    }
  }
  red[t] = acc;
  __syncthreads();
  for (int s = 128; s >= 1; s >>= 1) {
    if (t < s) red[t] += red[t + s];
    __syncthreads();
  }
  if (t == 0) ws[b] = -0.5f * red[0];
}

__global__ void finalize_kernel(const float* __restrict__ ws,
                                float* __restrict__ out, int B)
{
  int b = blockIdx.x * 256 + threadIdx.x;
  if (b < B) {
    float lj = ws[b];
    float la_u = ws[B + b], la_d = ws[2 * B + b];
    float s_u = ws[3 * B + b], s_d = ws[4 * B + b];
    out[b] = s_u * s_d;
    out[B + b] = lj + la_u + la_d;
  }
}

extern "C" void kernel_launch(void* const* d_in, const int* in_sizes, int n_in,
                              void* d_out, int out_size, void* d_ws, size_t ws_size,
                              hipStream_t stream) {
  const int* n = (const int*)d_in[0];
  const float* phi_up = (const float*)d_in[1];
  const float* phi_dn = (const float*)d_in[2];
  const float* v = (const float*)d_in[3];
  float* out = (float*)d_out;
  float* ws = (float*)d_ws;
  const int B = in_sizes[0] / NMODES;  // 4096

  jastrow_kernel<<<B, 256, 0, stream>>>(n, v, ws, B);
  lu_kernel<<<2 * B, 256, 0, stream>>>(n, phi_up, phi_dn, ws, B);
  finalize_kernel<<<(B + 255) / 256, 256, 0, stream>>>(ws, out, B);
}